// Round 1
// baseline (267.166 us; speedup 1.0000x reference)
//
#include <hip/hip_runtime.h>
#include <cstdint>
#include <cstddef>

#define Bn 64
#define Tn 2048
#define Un 512
#define QSn 512
#define MSn 512

using f32x16 = __attribute__((ext_vector_type(16))) float;
using bf16x8 = __attribute__((ext_vector_type(8))) short;

__device__ __forceinline__ unsigned short f2bf(float x) {
    unsigned int u = __float_as_uint(x);
    u += 0x7FFFu + ((u >> 16) & 1u);
    return (unsigned short)(u >> 16);
}

// ---------------- Wm f32 -> bf16 pre-convert ----------------
__global__ __launch_bounds__(256) void cvt_kernel(const float* __restrict__ src,
                                                  unsigned short* __restrict__ dst) {
    int i = blockIdx.x * 256 + threadIdx.x;  // one float4 per thread
    float4 v = *(const float4*)(src + (size_t)i * 4);
    ushort4 h = { f2bf(v.x), f2bf(v.y), f2bf(v.z), f2bf(v.w) };
    *(ushort4*)&dst[(size_t)i * 4] = h;
}

// ---------------- pq = query @ Wq^T : [B,U] ----------------
__global__ __launch_bounds__(128) void pq_kernel(const float* __restrict__ query,
                                                 const float* __restrict__ Wq,
                                                 float* __restrict__ pq) {
    __shared__ float ql[QSn];
    const int b = blockIdx.x;
    const int quad = blockIdx.y;
    const int tid = threadIdx.x;
    for (int i = tid; i < QSn; i += 128) ql[i] = query[(size_t)b * QSn + i];
    __syncthreads();
    const int u = quad * 128 + tid;
    const float* w = Wq + (size_t)u * QSn;
    float a0 = 0.f, a1 = 0.f;
    #pragma unroll 4
    for (int k = 0; k < QSn; k += 8) {
        float4 w0 = *(const float4*)(w + k);
        float4 w1 = *(const float4*)(w + k + 4);
        float4 q0 = *(const float4*)(ql + k);
        float4 q1 = *(const float4*)(ql + k + 4);
        a0 += w0.x * q0.x + w0.y * q0.y + w0.z * q0.z + w0.w * q0.w;
        a1 += w1.x * q1.x + w1.y * q1.y + w1.z * q1.z + w1.w * q1.w;
    }
    pq[(size_t)b * Un + u] = a0 + a1;
}

// ---------------- fused score GEMM ----------------
// block: 8 waves (512 thr), tile BM=128 t-rows x full U=512, BK=32.
// wave grid 2(m) x 4(n): wave tile 64x128 via 2x4 mfma_32x32x16 frags.
// epilogue: score[t] = sum_u tanh(vals + pq[u]) * Wa[u], reduced in-block.
#define BM 128
#define BK 32

__global__ __launch_bounds__(512) void score_kernel(const float* __restrict__ keys,
                                                    const unsigned short* __restrict__ WmB,
                                                    const float* __restrict__ pq,
                                                    const float* __restrict__ Wa,
                                                    float* __restrict__ score) {
    __shared__ unsigned short Alds[BM * BK];   // bf16, XOR-swizzled 16B granules
    __shared__ unsigned short Blds[Un * BK];
    __shared__ float pq_lds[Un];
    __shared__ float wa_lds[Un];
    __shared__ float sc_lds[4][BM];

    const int tid = threadIdx.x;
    const int b = blockIdx.y;
    const int t0 = blockIdx.x * BM;

    pq_lds[tid] = pq[(size_t)b * Un + tid];
    wa_lds[tid] = Wa[tid];

    const int lane = tid & 63;
    const int wid = tid >> 6;
    const int wm = wid >> 2;   // 0..1
    const int wn = wid & 3;    // 0..3

    f32x16 acc[2][4];
    #pragma unroll
    for (int mf = 0; mf < 2; ++mf)
        #pragma unroll
        for (int nf = 0; nf < 4; ++nf)
            #pragma unroll
            for (int r = 0; r < 16; ++r) acc[mf][nf][r] = 0.f;

    const float* keyA = keys + ((size_t)b * Tn + t0) * MSn;

    for (int k0 = 0; k0 < MSn; k0 += BK) {
        __syncthreads();
        // stage A: 128x32 f32 -> bf16 (2 float4 per thread)
        #pragma unroll
        for (int p = 0; p < 2; ++p) {
            int i = (p * 512 + tid) * 4;
            int row = i >> 5, col = i & 31;
            float4 v = *(const float4*)(keyA + (size_t)row * MSn + k0 + col);
            int gs = (col >> 3) ^ (row & 3);
            ushort4 h = { f2bf(v.x), f2bf(v.y), f2bf(v.z), f2bf(v.w) };
            *(ushort4*)&Alds[row * BK + gs * 8 + (col & 4)] = h;
        }
        // stage B: 512x32 bf16 (4 x 16B per thread, no conversion)
        #pragma unroll
        for (int p = 0; p < 4; ++p) {
            int i = (p * 512 + tid) * 8;
            int row = i >> 5, col = i & 31;   // col in {0,8,16,24}
            uint4 v = *(const uint4*)(WmB + (size_t)row * MSn + k0 + col);
            int gs = (col >> 3) ^ (row & 3);
            *(uint4*)&Blds[row * BK + gs * 8] = v;
        }
        __syncthreads();
        #pragma unroll
        for (int kk = 0; kk < 2; ++kk) {
            const int gb = kk * 2 + (lane >> 5);
            bf16x8 af[2], bfr[4];
            #pragma unroll
            for (int mf = 0; mf < 2; ++mf) {
                int r = wm * 64 + mf * 32 + (lane & 31);
                af[mf] = *(const bf16x8*)&Alds[r * BK + (gb ^ (r & 3)) * 8];
            }
            #pragma unroll
            for (int nf = 0; nf < 4; ++nf) {
                int r = wn * 128 + nf * 32 + (lane & 31);
                bfr[nf] = *(const bf16x8*)&Blds[r * BK + (gb ^ (r & 3)) * 8];
            }
            #pragma unroll
            for (int mf = 0; mf < 2; ++mf)
                #pragma unroll
                for (int nf = 0; nf < 4; ++nf)
                    acc[mf][nf] = __builtin_amdgcn_mfma_f32_32x32x16_bf16(
                        af[mf], bfr[nf], acc[mf][nf], 0, 0, 0);
        }
    }

    // epilogue: tanh + Wa-weighted row reduction
    // C/D layout (verified): col = lane&31, row = (reg&3) + 8*(reg>>2) + 4*(lane>>5)
    const int c = lane & 31;
    const int h = lane >> 5;
    float pqv[4], wav[4];
    #pragma unroll
    for (int nf = 0; nf < 4; ++nf) {
        int u = wn * 128 + nf * 32 + c;
        pqv[nf] = pq_lds[u];
        wav[nf] = wa_lds[u];
    }
    float part[2][16];
    #pragma unroll
    for (int mf = 0; mf < 2; ++mf) {
        #pragma unroll
        for (int r = 0; r < 16; ++r) {
            float s = 0.f;
            #pragma unroll
            for (int nf = 0; nf < 4; ++nf)
                s += tanhf(acc[mf][nf][r] + pqv[nf]) * wav[nf];
            // butterfly sum over the 32 columns this half-wave covers
            s += __shfl_xor(s, 16);
            s += __shfl_xor(s, 8);
            s += __shfl_xor(s, 4);
            s += __shfl_xor(s, 2);
            s += __shfl_xor(s, 1);
            part[mf][r] = s;
        }
    }
    if (c == 0) {
        #pragma unroll
        for (int mf = 0; mf < 2; ++mf)
            #pragma unroll
            for (int r = 0; r < 16; ++r) {
                int row = wm * 64 + mf * 32 + (r & 3) + 8 * (r >> 2) + 4 * h;
                sc_lds[wn][row] = part[mf][r];
            }
    }
    __syncthreads();
    if (tid < BM) {
        float s = sc_lds[0][tid] + sc_lds[1][tid] + sc_lds[2][tid] + sc_lds[3][tid];
        score[(size_t)b * Tn + t0 + tid] = s;
    }
}

// ---------------- softmax over T per batch ----------------
__global__ __launch_bounds__(256) void softmax_kernel(const float* __restrict__ score,
                                                      float* __restrict__ weight) {
    const int b = blockIdx.x, tid = threadIdx.x;
    const int lane = tid & 63, wid = tid >> 6;
    __shared__ float red[4];
    const float* s = score + (size_t)b * Tn;
    float v[8];
    float mx = -1e30f;
    #pragma unroll
    for (int i = 0; i < 8; ++i) { v[i] = s[tid + i * 256]; mx = fmaxf(mx, v[i]); }
    #pragma unroll
    for (int off = 32; off; off >>= 1) mx = fmaxf(mx, __shfl_xor(mx, off));
    if (lane == 0) red[wid] = mx;
    __syncthreads();
    mx = fmaxf(fmaxf(red[0], red[1]), fmaxf(red[2], red[3]));
    float sum = 0.f;
    #pragma unroll
    for (int i = 0; i < 8; ++i) { v[i] = expf(v[i] - mx); sum += v[i]; }
    #pragma unroll
    for (int off = 32; off; off >>= 1) sum += __shfl_xor(sum, off);
    __syncthreads();
    if (lane == 0) red[wid] = sum;
    __syncthreads();
    sum = red[0] + red[1] + red[2] + red[3];
    float inv = 1.f / sum;
    #pragma unroll
    for (int i = 0; i < 8; ++i) weight[(size_t)b * Tn + tid + i * 256] = v[i] * inv;
}

// ---------------- context partials: 16 t-chunks per batch ----------------
__global__ __launch_bounds__(256) void ctx_partial_kernel(const float* __restrict__ keys,
                                                          const float* __restrict__ weight,
                                                          float* __restrict__ partial) {
    __shared__ float wl[128];
    const int b = blockIdx.x, chunk = blockIdx.y, tid = threadIdx.x;
    const int t0 = chunk * 128;
    if (tid < 128) wl[tid] = weight[(size_t)b * Tn + t0 + tid];
    __syncthreads();
    float2 acc = { 0.f, 0.f };
    const float2* kp = (const float2*)(keys + ((size_t)b * Tn + t0) * MSn);
    #pragma unroll 4
    for (int t = 0; t < 128; ++t) {
        float2 kv = kp[(size_t)t * (MSn / 2) + tid];
        float w = wl[t];
        acc.x += w * kv.x;
        acc.y += w * kv.y;
    }
    *(float2*)&partial[((size_t)b * 16 + chunk) * MSn + tid * 2] = acc;
}

// ---------------- reduce partials -> total_context ----------------
__global__ __launch_bounds__(512) void ctx_reduce_kernel(const float* __restrict__ partial,
                                                         float* __restrict__ ctx) {
    const int b = blockIdx.x, m = threadIdx.x;
    float s = 0.f;
    #pragma unroll
    for (int c = 0; c < 16; ++c) s += partial[((size_t)b * 16 + c) * MSn + m];
    ctx[(size_t)b * MSn + m] = s;
}

extern "C" void kernel_launch(void* const* d_in, const int* in_sizes, int n_in,
                              void* d_out, int out_size, void* d_ws, size_t ws_size,
                              hipStream_t stream) {
    const float* query = (const float*)d_in[0];
    const float* keys  = (const float*)d_in[1];
    const float* Wq    = (const float*)d_in[2];
    const float* Wm    = (const float*)d_in[3];
    const float* Wa    = (const float*)d_in[4];

    float* ctx_out   = (float*)d_out;                   // [64][512]
    float* score_out = (float*)d_out + (size_t)Bn * MSn; // [64][2048]

    char* ws = (char*)d_ws;
    float* ws_pq      = (float*)(ws);                    // 128 KB
    float* ws_weight  = (float*)(ws + 131072);           // 512 KB
    float* ws_partial = (float*)(ws + 655360);           // 2 MB
    unsigned short* ws_wmbf = (unsigned short*)(ws + 2752512);  // 512 KB

    cvt_kernel<<<(Un * MSn / 4) / 256, 256, 0, stream>>>(Wm, ws_wmbf);
    pq_kernel<<<dim3(Bn, 4), 128, 0, stream>>>(query, Wq, ws_pq);
    score_kernel<<<dim3(Tn / BM, Bn), 512, 0, stream>>>(keys, ws_wmbf, ws_pq, Wa, score_out);
    softmax_kernel<<<Bn, 256, 0, stream>>>(score_out, ws_weight);
    ctx_partial_kernel<<<dim3(Bn, 16), 256, 0, stream>>>(keys, ws_weight, ws_partial);
    ctx_reduce_kernel<<<Bn, 512, 0, stream>>>(ws_partial, ctx_out);
}